// Round 1
// 118.706 us; speedup vs baseline: 1.0475x; 1.0475x over previous
//
#include <hip/hip_runtime.h>

// Problem constants (fixed by setup_inputs): B=4096, D=512, H=W=64, N=4096.
#define B_ROWS 4096
#define N_COLS 4096
#define DIM    512
#define LDK    1024   // row stride (elements) of split bf16 arrays [hi(512) | lo(512)]

typedef __attribute__((ext_vector_type(8))) short short8;
typedef __attribute__((ext_vector_type(4))) float floatx4;

// bf16 round-to-nearest-even split helpers (bit-exact, no API dependence)
__device__ __forceinline__ unsigned short f2bf_rn(float f) {
    unsigned u = __float_as_uint(f);
    u += 0x7fffu + ((u >> 16) & 1u);
    return (unsigned short)(u >> 16);
}
__device__ __forceinline__ float bf2f(unsigned short h) {
    return __uint_as_float(((unsigned)h) << 16);
}

// Monotone float->uint map; (key<<32)|idx gives u64 atomicMin argmin with
// smallest-index tie-break (matches numpy argmin semantics).
__device__ __forceinline__ unsigned long long pack_key(float v, int idx) {
    unsigned u = __float_as_uint(v);
    u = (u & 0x80000000u) ? ~u : (u | 0x80000000u);
    return ((unsigned long long)u << 32) | (unsigned)idx;
}

// Async global->LDS, 16B per lane. LDS dest is wave-uniform base + lane*16.
// Global source address IS per-lane (m173), which lets us stage arbitrary
// gather patterns into linear LDS.
__device__ __forceinline__ void async16(const unsigned short* g, unsigned short* l) {
    __builtin_amdgcn_global_load_lds(
        (__attribute__((address_space(1))) void*)g,
        (__attribute__((address_space(3))) void*)l, 16, 0, 0);
}

// One wave per row (4 rows/block): split fp32 row into bf16 hi/lo halves,
// compute exact fp32 ||row||^2, init packed argmin accumulators. (unchanged)
__global__ __launch_bounds__(256) void som_convert(
    const float* __restrict__ X, const float* __restrict__ Wt,
    unsigned short* __restrict__ Xc, unsigned short* __restrict__ Wc,
    float* __restrict__ x_sq, float* __restrict__ w_sq,
    unsigned long long* __restrict__ packed)
{
    int wave = threadIdx.x >> 6, lane = threadIdx.x & 63;
    int grow = blockIdx.x * 4 + wave;            // 0..8191
    bool isX = grow < B_ROWS;
    const float* src = isX ? (X + (size_t)grow * DIM)
                           : (Wt + (size_t)(grow - B_ROWS) * DIM);
    const float4* p4 = (const float4*)src;
    float4 a = p4[lane * 2], b = p4[lane * 2 + 1];
    float f[8] = {a.x, a.y, a.z, a.w, b.x, b.y, b.z, b.w};
    unsigned short hi[8], lo[8];
    float s = 0.f;
    #pragma unroll
    for (int t = 0; t < 8; ++t) {
        hi[t] = f2bf_rn(f[t]);
        lo[t] = f2bf_rn(f[t] - bf2f(hi[t]));
        s = fmaf(f[t], f[t], s);
    }
    unsigned short* dst = (isX ? Xc + (size_t)grow * LDK
                               : Wc + (size_t)(grow - B_ROWS) * LDK) + lane * 8;
    *(ushort4*)(dst)       = make_ushort4(hi[0], hi[1], hi[2], hi[3]);
    *(ushort4*)(dst + 4)   = make_ushort4(hi[4], hi[5], hi[6], hi[7]);
    *(ushort4*)(dst + 512) = make_ushort4(lo[0], lo[1], lo[2], lo[3]);
    *(ushort4*)(dst + 516) = make_ushort4(lo[4], lo[5], lo[6], lo[7]);
    #pragma unroll
    for (int off = 32; off >= 1; off >>= 1) s += __shfl_xor(s, off, 64);
    if (lane == 0) {
        if (isX) { x_sq[grow] = s; packed[grow] = ~0ull; }
        else     { w_sq[grow - B_ROWS] = s; }
    }
}

// ---------------------------------------------------------------------------
// Split-bf16 distance GEMM v2: 256x256 tile, 8 waves (2x4), BK=32,
// double-buffered LDS (128 KB), issue-early pipelined staging (1 barrier per
// K-step, loads have a full iteration of MFMA cover), fragment-order LDS
// subtiles (zero bank conflicts on both staging writes and ds_read_b128),
// setprio around each 32-MFMA cluster.
//
// LDS image per buffer: 64 subtiles x 1KB. Subtile = 16 rows x 32 k of one
// operand half, stored in MFMA fragment order: word l = row (l&15),
// k-elems (l>>4)*8..+8. A: sidx = rbl*2+h (rbl 0..15). B: sidx = 32+rbl*2+h.
// Math/order identical to v1 (hh, h*bl, al*h per 32-k slice) => bit-exact.
// ---------------------------------------------------------------------------
__global__ __launch_bounds__(512, 2) void som_dist_v2(
    const unsigned short* __restrict__ Xc, const unsigned short* __restrict__ Wc,
    const float* __restrict__ w_sq, unsigned long long* __restrict__ packed)
{
    __shared__ __align__(16) unsigned short L[2 * 64 * 512];   // 128 KiB
    const int tid  = threadIdx.x;
    const int wave = tid >> 6, lane = tid & 63;
    const int quad = lane >> 4, t16 = lane & 15;
    const int wr = wave >> 2, wc = wave & 3;       // 2x4 wave grid (128x64 out/wave)
    const int bm = blockIdx.y, bn = blockIdx.x;

    // --- staging role: waves 0-3 stage A (X), waves 4-7 stage B (W).
    // Wave stages 8 subtiles: rbl in [sg*4, sg*4+4), h in {hi,lo}.
    const int sg = wave & 3;
    const bool stB = (wave >= 4);
    const unsigned short* gsrc =
        (stB ? Wc + (size_t)bn * 256 * LDK : Xc + (size_t)bm * 256 * LDK)
        + (size_t)(sg * 64 + t16) * LDK + quad * 8;
    unsigned short* const lwav = &L[(stB ? 16384 : 0) + sg * 4096];

    // --- fragment read bases (subtile-linear: lane*16B => conflict-free)
    const unsigned short* const pA = &L[wr * 8192 + lane * 8];
    const unsigned short* const pB = &L[16384 + wc * 4096 + lane * 8];

    floatx4 acc[8][4];
    #pragma unroll
    for (int i = 0; i < 8; ++i)
        #pragma unroll
        for (int j = 0; j < 4; ++j) acc[i][j] = (floatx4){0.f, 0.f, 0.f, 0.f};

    // --- prologue: stage tile 0 into buffer 0
    #pragma unroll
    for (int q = 0; q < 4; ++q) {
        async16(gsrc + q * 16 * LDK,       lwav + q * 1024);
        async16(gsrc + q * 16 * LDK + 512, lwav + q * 1024 + 512);
    }
    __syncthreads();   // implicit vmcnt(0): tile 0 visible to all waves

    #pragma unroll 2
    for (int kt = 0; kt < 16; ++kt) {
        const int cur = kt & 1;
        const unsigned short* pAc = pA + cur * 32768;
        const unsigned short* pBc = pB + cur * 32768;

        // Issue next tile's staging FIRST: these loads get the whole
        // iteration's 96 MFMAs of latency cover before the end barrier drains
        // them. Writes go to buf (1-cur), which all waves finished reading
        // before the previous barrier.
        if (kt < 15) {
            const unsigned short* gs = gsrc + (kt + 1) * 32;
            unsigned short* ld = lwav + (cur ^ 1) * 32768;
            #pragma unroll
            for (int q = 0; q < 4; ++q) {
                async16(gs + q * 16 * LDK,       ld + q * 1024);
                async16(gs + q * 16 * LDK + 512, ld + q * 1024 + 512);
            }
        }

        // Phase 1: ah x bh
        short8 ah[8], bh[4], x4[4];
        #pragma unroll
        for (int i = 0; i < 8; ++i) ah[i] = *(const short8*)(pAc + i * 1024);
        #pragma unroll
        for (int j = 0; j < 4; ++j) bh[j] = *(const short8*)(pBc + j * 1024);
        __builtin_amdgcn_s_setprio(1);
        #pragma unroll
        for (int i = 0; i < 8; ++i)
            #pragma unroll
            for (int j = 0; j < 4; ++j)
                acc[i][j] = __builtin_amdgcn_mfma_f32_16x16x32_bf16(
                    ah[i], bh[j], acc[i][j], 0, 0, 0);
        __builtin_amdgcn_s_setprio(0);

        // Phase 2: ah x bl
        #pragma unroll
        for (int j = 0; j < 4; ++j) x4[j] = *(const short8*)(pBc + j * 1024 + 512);
        __builtin_amdgcn_s_setprio(1);
        #pragma unroll
        for (int i = 0; i < 8; ++i)
            #pragma unroll
            for (int j = 0; j < 4; ++j)
                acc[i][j] = __builtin_amdgcn_mfma_f32_16x16x32_bf16(
                    ah[i], x4[j], acc[i][j], 0, 0, 0);
        __builtin_amdgcn_s_setprio(0);

        // Phase 3: al x bh
        short8 al[8];
        #pragma unroll
        for (int i = 0; i < 8; ++i) al[i] = *(const short8*)(pAc + i * 1024 + 512);
        __builtin_amdgcn_s_setprio(1);
        #pragma unroll
        for (int i = 0; i < 8; ++i)
            #pragma unroll
            for (int j = 0; j < 4; ++j)
                acc[i][j] = __builtin_amdgcn_mfma_f32_16x16x32_bf16(
                    al[i], bh[j], acc[i][j], 0, 0, 0);
        __builtin_amdgcn_s_setprio(0);

        // One barrier per K-step: drains vmcnt (next tile landed) + syncs all
        // waves' ds_reads of buf[cur] before it is overwritten next iter.
        __syncthreads();
    }

    // Epilogue: val = w_sq - 2*dot (x_sq is per-row constant, irrelevant to
    // argmin). C/D layout: col = t16, row = quad*4 + reg  [m89/m91].
    const int col0 = bn * 256 + wc * 64 + t16;
    float wq[4];
    #pragma unroll
    for (int j = 0; j < 4; ++j) wq[j] = w_sq[col0 + j * 16];
    const int row_base = bm * 256 + wr * 128 + quad * 4;
    #pragma unroll
    for (int i = 0; i < 8; ++i) {
        #pragma unroll
        for (int r = 0; r < 4; ++r) {
            unsigned long long best = ~0ull;
            #pragma unroll
            for (int j = 0; j < 4; ++j) {
                float val = fmaf(-2.f, acc[i][j][r], wq[j]);
                unsigned long long key = pack_key(val, col0 + j * 16);
                best = (key < best) ? key : best;
            }
            #pragma unroll
            for (int m = 1; m <= 8; m <<= 1) {     // reduce 16-lane col group
                unsigned long long o = __shfl_xor(best, m, 64);
                best = (o < best) ? o : best;
            }
            if (t16 == 0)
                atomicMin(&packed[row_base + i * 16 + r], best);
        }
    }
}

// Unpack argmin, qe = sqrt(max(||x||^2 + val, 0)).
// d_out: bmu_indices (4096 x 2) flat, then qe (4096), all float. (unchanged)
__global__ __launch_bounds__(256) void som_finalize(
    const unsigned long long* __restrict__ packed,
    const float* __restrict__ x_sq, float* __restrict__ out)
{
    int b = blockIdx.x * 256 + threadIdx.x;  // 0..4095
    unsigned long long p = packed[b];
    unsigned idx = (unsigned)(p & 0xffffffffull);
    unsigned key = (unsigned)(p >> 32);
    unsigned u = (key & 0x80000000u) ? (key & 0x7fffffffu) : ~key;
    float val = __uint_as_float(u);
    float sq = fmaxf(x_sq[b] + val, 0.f);
    out[2 * b]     = (float)(idx >> 6);   // y = idx / 64
    out[2 * b + 1] = (float)(idx & 63);   // x = idx % 64
    out[2 * B_ROWS + b] = sqrtf(sq);
}

extern "C" void kernel_launch(void* const* d_in, const int* in_sizes, int n_in,
                              void* d_out, int out_size, void* d_ws, size_t ws_size,
                              hipStream_t stream) {
    const float* X  = (const float*)d_in[0];   // (4096, 512)
    const float* Wt = (const float*)d_in[1];   // (64, 64, 512) -> (4096, 512)
    float* out = (float*)d_out;

    // ws layout: [0,32K) packed u64[4096]; [32K,48K) x_sq; [48K,64K) w_sq;
    // [64K, 64K+8M) Xc bf16 split; [64K+8M, 64K+16M) Wc bf16 split.
    unsigned long long* packed = (unsigned long long*)d_ws;
    float* x_sq = (float*)((char*)d_ws + (32 << 10));
    float* w_sq = (float*)((char*)d_ws + (48 << 10));
    unsigned short* Xc = (unsigned short*)((char*)d_ws + (64 << 10));
    unsigned short* Wc = (unsigned short*)((char*)d_ws + (64 << 10) + ((size_t)B_ROWS * LDK * 2));

    som_convert<<<dim3((B_ROWS + N_COLS) / 4), dim3(256), 0, stream>>>(
        X, Wt, Xc, Wc, x_sq, w_sq, packed);
    som_dist_v2<<<dim3(N_COLS / 256, B_ROWS / 256), dim3(512), 0, stream>>>(
        Xc, Wc, w_sq, packed);
    som_finalize<<<dim3(B_ROWS / 256), dim3(256), 0, stream>>>(packed, x_sq, out);
}